// Round 5
// baseline (402.865 us; speedup 1.0000x reference)
//
#include <hip/hip_runtime.h>

#define B_ 8
#define T_ 256
#define U_ 65
#define D_ 512
#define TU (T_*U_)
#define LSTRIDE 66          // +1 pad over U: diagonal access = 2 lanes/bank (free)
#define NEGINF (-1e30f)
#define SLACK_ROWS 64
// LDS word layout: la[256*66] | bl[256*66] | slack[64*66]=NEGINF.
// la upper-overrun (t>255) reads into bl (finite, harmless);
// bl upper-overrun reads into slack (NEGINF). Lower side uses max(.,0) clamp,
// which is value-exact because alpha is NEGINF there.
#define LA_OFF 0
#define BL_OFF (T_*LSTRIDE)
#define LDS_WORDS (2*T_*LSTRIDE + SLACK_ROWS*LSTRIDE)

typedef float nfloat4 __attribute__((ext_vector_type(4)));

__device__ __forceinline__ float pick4(const float4 c, int j) {
    return j == 0 ? c.x : (j == 1 ? c.y : (j == 2 ? c.z : c.w));
}

__device__ __forceinline__ float laddexp(float a, float b) {
    float mx = fmaxf(a, b);
    float mn = fminf(a, b);
    return mx + __logf(1.0f + __expf(mn - mx));
}

// lane i <- lane i-1; lane 0 gets NEGINF (kills the label branch exactly)
__device__ __forceinline__ float wave_shr1(float x) {
    return __int_as_float(__builtin_amdgcn_update_dpp(
        __float_as_int(NEGINF), __float_as_int(x),
        0x138 /*wave_shr:1*/, 0xf, 0xf, false));
}

// Kernel 1 (unchanged from round 4): per-row log-softmax, no max-reduction.
__global__ __launch_bounds__(256) void lp_kernel(
        const float* __restrict__ logits,
        const int* __restrict__ targets,
        float* __restrict__ blank_lp,
        float* __restrict__ label_lp) {
    const int tid  = threadIdx.x;
    const int lane = tid & 63;
    const int w    = tid >> 6;
    const int r    = blockIdx.x * 4 + w;
    const int b    = r / TU;
    const int rem  = r - b * TU;
    const int u    = rem % U_;

    const float* row = logits + (size_t)r * D_;
    const nfloat4 n0 = __builtin_nontemporal_load((const nfloat4*)(row + lane * 4));
    const nfloat4 n1 = __builtin_nontemporal_load((const nfloat4*)(row + 256 + lane * 4));
    const float4 c0 = {n0.x, n0.y, n0.z, n0.w};
    const float4 c1 = {n1.x, n1.y, n1.z, n1.w};

    float s = __expf(c0.x) + __expf(c0.y) + __expf(c0.z) + __expf(c0.w)
            + __expf(c1.x) + __expf(c1.y) + __expf(c1.z) + __expf(c1.w);
    #pragma unroll
    for (int off = 32; off >= 1; off >>= 1)
        s += __shfl_xor(s, off);

    const float logZ = __logf(s);

    if (lane == 63)
        blank_lp[r] = c1.w - logZ;

    const int lab = (u < U_ - 1) ? targets[b * (U_ - 1) + u] : 0;
    const int lo  = (lab & 255) >> 2;
    const int j   = lab & 3;
    if (lane == lo) {
        const float v = (lab >= 256) ? pick4(c1, j) : pick4(c0, j);
        label_lp[r] = v - logZ;
    }
}

// Kernel 2: uniform anti-diagonal DP, d = 1..319, zero predication,
// LDS operands software-pipelined one diagonal ahead.
__global__ __launch_bounds__(256) void dp_kernel(
        const float* __restrict__ blank_g,
        const float* __restrict__ label_g,
        const int* __restrict__ src_len,
        const int* __restrict__ tgt_len,
        float* __restrict__ out) {
    extern __shared__ float lds[];
    float* la = lds + LA_OFF;        // [256][66]
    float* bl = lds + BL_OFF;        // [256][66]

    const int b   = blockIdx.x;
    const int tid = threadIdx.x;
    const int base = b * TU;

    for (int i = tid * 4; i < TU; i += 256 * 4) {
        const float4 vb = *(const float4*)(blank_g + base + i);
        const float4 vl = *(const float4*)(label_g + base + i);
        #pragma unroll
        for (int j = 0; j < 4; ++j) {
            const int idx = i + j;
            const int t = idx / U_;
            const int c = idx - t * U_;
            bl[t * LSTRIDE + c] = pick4(vb, j);
            la[t * LSTRIDE + c] = pick4(vl, j);
        }
    }
    for (int i = tid; i < SLACK_ROWS * LSTRIDE; i += 256)
        lds[2 * T_ * LSTRIDE + i] = NEGINF;
    __syncthreads();
    if (tid >= 64) return;           // single compute wave

    const int u    = tid;
    const int colL = (u == 0) ? 0 : (u - 1);
    const int tI = src_len[b] - 1;
    const int uI = tgt_len[b];
    const int dcapU  = tI + u;
    const int dcap64 = tI + 64;

    // peel d=0: cell (0,0) = 0
    float alpha = (u == 0) ? 0.0f : NEGINF;  // entering d=1: alpha[-u][u]
    float a64   = NEGINF;                    // lane 63's copy is column 64
    float res   = (dcapU == 0) ? alpha : NEGINF;
    float res64 = NEGINF;

    #define ADDR_B(d) (max((d) - u - 1, 0) * LSTRIDE + u)
    #define ADDR_L(d) (max((d) - u,     0) * LSTRIDE + colL)

    float blv = bl[ADDR_B(1)];
    float lav = la[ADDR_L(1)];
    float b64 = bl[64];                       // row max(1-65,0)=0, col 64
    float l64 = la[63];                       // row max(1-64,0)=0, col 63

    for (int d = 1; d <= T_ + U_ - 2; ++d) {
        // prefetch d+1 (d=320 overruns land in slack/adjacent region: finite)
        const float blv_n = bl[ADDR_B(d + 1)];
        const float lav_n = la[ADDR_L(d + 1)];
        const float b64_n = bl[max(d - 64, 0) * LSTRIDE + 64];
        const float l64_n = la[max(d - 63, 0) * LSTRIDE + 63];

        // column 64: uses this lane's entering alpha (lane 63's is the real one)
        a64 = laddexp(a64 + b64, alpha + l64);
        res64 = (d == dcap64) ? a64 : res64;

        // main cell (d-u, u)
        const float aUm1 = wave_shr1(alpha);
        const float val = laddexp(alpha + blv, aUm1 + lav);
        res = (d == dcapU) ? val : res;
        alpha = val;

        blv = blv_n; lav = lav_n; b64 = b64_n; l64 = l64_n;
    }
    #undef ADDR_B
    #undef ADDR_L

    const float afin = (uI >= U_ - 1) ? __shfl(res64, 63) : __shfl(res, uI);
    if (tid == 0)
        out[b] = -(afin + bl[tI * LSTRIDE + uI]);
}

extern "C" void kernel_launch(void* const* d_in, const int* in_sizes, int n_in,
                              void* d_out, int out_size, void* d_ws, size_t ws_size,
                              hipStream_t stream) {
    const float* logits  = (const float*)d_in[0];
    const int*   targets = (const int*)d_in[1];
    const int*   src_len = (const int*)d_in[2];
    const int*   tgt_len = (const int*)d_in[3];
    float* out = (float*)d_out;

    float* blank_lp = (float*)d_ws;
    float* label_lp = blank_lp + (size_t)B_ * TU;

    lp_kernel<<<B_ * TU / 4, 256, 0, stream>>>(logits, targets, blank_lp, label_lp);

    const int shmem = LDS_WORDS * (int)sizeof(float);   // 152,064 B
    (void)hipFuncSetAttribute((const void*)dp_kernel,
                              hipFuncAttributeMaxDynamicSharedMemorySize, shmem);
    dp_kernel<<<B_, 256, shmem, stream>>>(blank_lp, label_lp, src_len, tgt_len, out);
}